// Round 3
// baseline (251.453 us; speedup 1.0000x reference)
//
#include <hip/hip_runtime.h>
#include <hip/hip_bf16.h>
#include <stdint.h>

// Problem constants
constexpr int cB = 2;
constexpr int cS = 2048;
constexpr int cH = 1024;
constexpr int cNH = 16;
constexpr int cHD = 64;
constexpr int cBS = cB * cS;  // 4096

typedef short short8 __attribute__((ext_vector_type(8)));
typedef float f32x4 __attribute__((ext_vector_type(4)));

__device__ inline unsigned short f2bf(float f) {
  union { float f; unsigned u; } v; v.f = f;
  unsigned r = v.u + 0x7FFF + ((v.u >> 16) & 1);  // RNE
  return (unsigned short)(r >> 16);
}

// ---------------- QKV GEMM: C[i,o] = sum_k X[i,k] * W[o,k] + b[o] ----------------
// fp32 inputs, bf16 output (Q/K/V scratch). Reg-staged LDS (f32x4 -> bf16 -> ds_write).
// 128x128 tile, BK=32, 4 waves (2x2), each wave 64x64 (4x4 MFMA frags).
constexpr int BM = 128, BN = 128, BK = 32;

__global__ __launch_bounds__(256) void qkv_gemm(
    const float* __restrict__ X,   // [4096][1024]
    const float* __restrict__ Wq,  // [1024][1024] (row=out, col=in)
    const float* __restrict__ Wk,
    const float* __restrict__ Wv,
    const float* __restrict__ bq, const float* __restrict__ bk,
    const float* __restrict__ bv,
    unsigned short* __restrict__ Qb, unsigned short* __restrict__ Kb,
    unsigned short* __restrict__ Vb) {
  __shared__ alignas(16) unsigned short As[BM * BK];  // [128][32]
  __shared__ alignas(16) unsigned short Bs[BN * BK];

  const int nb = blockIdx.x;  // 0..23
  const int mb = blockIdx.y;  // 0..31
  const int m0 = mb * BM;
  const int wsel = nb >> 3;
  const int n0 = (nb & 7) * BN;  // col within this W's 1024
  const float* W = (wsel == 0) ? Wq : (wsel == 1 ? Wk : Wv);
  const float* bias = (wsel == 0) ? bq : (wsel == 1 ? bk : bv);
  unsigned short* Out = (wsel == 0) ? Qb : (wsel == 1 ? Kb : Vb);

  const int t = threadIdx.x;
  const int w = t >> 6, l = t & 63, lr = l & 15, lg = l >> 4;
  const int wm = w >> 1, wn = w & 1;
  // staging assignment: 2 threads per row, 16 fp32 each
  const int srow = t >> 1;
  const int scol = (t & 1) * 16;

  f32x4 acc[4][4];
#pragma unroll
  for (int mi = 0; mi < 4; ++mi)
#pragma unroll
    for (int ni = 0; ni < 4; ++ni) acc[mi][ni] = {0.f, 0.f, 0.f, 0.f};

  for (int kt = 0; kt < cH / BK; ++kt) {
    const int k0 = kt * BK;
    __syncthreads();  // previous iter's LDS reads done before overwrite
    // stage A tile
    {
      const float* s = X + (size_t)(m0 + srow) * cH + k0 + scol;
      f32x4 v0 = *reinterpret_cast<const f32x4*>(s);
      f32x4 v1 = *reinterpret_cast<const f32x4*>(s + 4);
      f32x4 v2 = *reinterpret_cast<const f32x4*>(s + 8);
      f32x4 v3 = *reinterpret_cast<const f32x4*>(s + 12);
      short8 o0, o1;
#pragma unroll
      for (int j = 0; j < 4; ++j) {
        o0[j] = (short)f2bf(v0[j]);
        o0[4 + j] = (short)f2bf(v1[j]);
        o1[j] = (short)f2bf(v2[j]);
        o1[4 + j] = (short)f2bf(v3[j]);
      }
      *reinterpret_cast<short8*>(&As[srow * BK + scol]) = o0;
      *reinterpret_cast<short8*>(&As[srow * BK + scol + 8]) = o1;
    }
    // stage B tile
    {
      const float* s = W + (size_t)(n0 + srow) * cH + k0 + scol;
      f32x4 v0 = *reinterpret_cast<const f32x4*>(s);
      f32x4 v1 = *reinterpret_cast<const f32x4*>(s + 4);
      f32x4 v2 = *reinterpret_cast<const f32x4*>(s + 8);
      f32x4 v3 = *reinterpret_cast<const f32x4*>(s + 12);
      short8 o0, o1;
#pragma unroll
      for (int j = 0; j < 4; ++j) {
        o0[j] = (short)f2bf(v0[j]);
        o0[4 + j] = (short)f2bf(v1[j]);
        o1[j] = (short)f2bf(v2[j]);
        o1[4 + j] = (short)f2bf(v3[j]);
      }
      *reinterpret_cast<short8*>(&Bs[srow * BK + scol]) = o0;
      *reinterpret_cast<short8*>(&Bs[srow * BK + scol + 8]) = o1;
    }
    __syncthreads();

    short8 af[4], bfr[4];
#pragma unroll
    for (int mi = 0; mi < 4; ++mi)
      af[mi] = *reinterpret_cast<const short8*>(
          &As[(wm * 64 + mi * 16 + lr) * BK + lg * 8]);
#pragma unroll
    for (int ni = 0; ni < 4; ++ni)
      bfr[ni] = *reinterpret_cast<const short8*>(
          &Bs[(wn * 64 + ni * 16 + lr) * BK + lg * 8]);
#pragma unroll
    for (int mi = 0; mi < 4; ++mi)
#pragma unroll
      for (int ni = 0; ni < 4; ++ni)
        acc[mi][ni] = __builtin_amdgcn_mfma_f32_16x16x32_bf16(
            af[mi], bfr[ni], acc[mi][ni], 0, 0, 0);
  }

  // epilogue: bias + bf16 store. C row = m0+wm*64+mi*16+lg*4+r, col = n0+wn*64+ni*16+lr
#pragma unroll
  for (int ni = 0; ni < 4; ++ni) {
    const int col = n0 + wn * 64 + ni * 16 + lr;
    const float bvv = bias[col];
#pragma unroll
    for (int mi = 0; mi < 4; ++mi) {
      const int row = m0 + wm * 64 + mi * 16 + lg * 4;
#pragma unroll
      for (int r = 0; r < 4; ++r)
        Out[(size_t)(row + r) * cH + col] = f2bf(acc[mi][ni][r] + bvv);
    }
  }
}

// ---------------- Flash attention ----------------
// Block = (qb, bh): 64 q-rows of one (b,h). 4 waves x 16 q-rows each.
// KV tiles of 64. Online softmax per q-row (spread over 16-lane groups).
// OUTPUT IS FP32 (reference output dtype is float32).
__global__ __launch_bounds__(256) void attn_kernel(
    const unsigned short* __restrict__ Qb,  // [B*S][H] bf16
    const unsigned short* __restrict__ Kb,
    const unsigned short* __restrict__ Vb,
    const float* __restrict__ mask,         // [B][S]
    float* __restrict__ out) {              // [B*S][H] fp32
  __shared__ alignas(16) unsigned short plds[4][16 * 64];  // per-wave P tile

  const int qb = blockIdx.x;  // 0..31
  const int bh = blockIdx.y;  // 0..31
  const int b = bh >> 4, h = bh & 15;
  const int t = threadIdx.x;
  const int w = t >> 6, l = t & 63, lr = l & 15, lg = l >> 4;
  const int q0 = qb * 64 + w * 16;

  const unsigned short* Qrow = Qb + (size_t)(b * cS + q0 + lr) * cH + h * cHD;
  short8 qf0 = *reinterpret_cast<const short8*>(Qrow + lg * 8);
  short8 qf1 = *reinterpret_cast<const short8*>(Qrow + 32 + lg * 8);

  f32x4 oacc[4];
#pragma unroll
  for (int d16 = 0; d16 < 4; ++d16) oacc[d16] = {0.f, 0.f, 0.f, 0.f};
  float mrow[4] = {-1e30f, -1e30f, -1e30f, -1e30f};
  float lsum[4] = {0.f, 0.f, 0.f, 0.f};

  const unsigned short* Kbase = Kb + (size_t)b * cS * cH + h * cHD;
  const unsigned short* Vbase = Vb + (size_t)b * cS * cH + h * cHD;
  const float* mbase = mask + b * cS;
  unsigned short* pw = &plds[w][0];

  for (int kt = 0; kt < cS / 64; ++kt) {
    const int kv0 = kt * 64;
    f32x4 sc[4];
#pragma unroll
    for (int n = 0; n < 4; ++n) {
      const unsigned short* Krow = Kbase + (size_t)(kv0 + n * 16 + lr) * cH;
      short8 kf0 = *reinterpret_cast<const short8*>(Krow + lg * 8);
      short8 kf1 = *reinterpret_cast<const short8*>(Krow + 32 + lg * 8);
      f32x4 z = {0.f, 0.f, 0.f, 0.f};
      z = __builtin_amdgcn_mfma_f32_16x16x32_bf16(qf0, kf0, z, 0, 0, 0);
      z = __builtin_amdgcn_mfma_f32_16x16x32_bf16(qf1, kf1, z, 0, 0, 0);
      const float mv = mbase[kv0 + n * 16 + lr];
      sc[n] = z * 0.125f + mv;
    }
    // online softmax; q-row (lg*4+r) values live on the 16 lanes sharing lg
    float scalef[4];
    unsigned short pb[4][4];  // [n][r]
#pragma unroll
    for (int r = 0; r < 4; ++r) {
      float mx = fmaxf(fmaxf(sc[0][r], sc[1][r]), fmaxf(sc[2][r], sc[3][r]));
#pragma unroll
      for (int d = 1; d < 16; d <<= 1) mx = fmaxf(mx, __shfl_xor(mx, d));
      const float mnew = fmaxf(mrow[r], mx);
      scalef[r] = __expf(mrow[r] - mnew);
      mrow[r] = mnew;
      float ps = 0.f;
#pragma unroll
      for (int n = 0; n < 4; ++n) {
        const float p = __expf(sc[n][r] - mnew);
        ps += p;
        pb[n][r] = f2bf(p);
      }
#pragma unroll
      for (int d = 1; d < 16; d <<= 1) ps += __shfl_xor(ps, d);
      lsum[r] = lsum[r] * scalef[r] + ps;
    }
#pragma unroll
    for (int d16 = 0; d16 < 4; ++d16)
#pragma unroll
      for (int r = 0; r < 4; ++r) oacc[d16][r] *= scalef[r];

    // P -> per-wave LDS tile [16][64], then PV
    __syncthreads();
#pragma unroll
    for (int r = 0; r < 4; ++r) {
      const int row = lg * 4 + r;
#pragma unroll
      for (int n = 0; n < 4; ++n) pw[row * 64 + n * 16 + lr] = pb[n][r];
    }
    __syncthreads();
#pragma unroll
    for (int ks2 = 0; ks2 < 2; ++ks2) {
      short8 pa =
          *reinterpret_cast<const short8*>(&pw[lr * 64 + ks2 * 32 + lg * 8]);
#pragma unroll
      for (int d16 = 0; d16 < 4; ++d16) {
        const unsigned short* vcol =
            Vbase + (size_t)(kv0 + ks2 * 32 + lg * 8) * cH + d16 * 16 + lr;
        short8 vf;
#pragma unroll
        for (int j = 0; j < 8; ++j) vf[j] = (short)vcol[(size_t)j * cH];
        oacc[d16] =
            __builtin_amdgcn_mfma_f32_16x16x32_bf16(pa, vf, oacc[d16], 0, 0, 0);
      }
    }
  }

  // fp32 store
  float* obase = out + (size_t)(b * cS + q0 + lg * 4) * cH + h * cHD;
#pragma unroll
  for (int r = 0; r < 4; ++r) {
    const float inv = 1.0f / lsum[r];
#pragma unroll
    for (int d16 = 0; d16 < 4; ++d16)
      obase[(size_t)r * cH + d16 * 16 + lr] = oacc[d16][r] * inv;
  }
}

// ---------------- launcher ----------------
extern "C" void kernel_launch(void* const* d_in, const int* in_sizes, int n_in,
                              void* d_out, int out_size, void* d_ws,
                              size_t ws_size, hipStream_t stream) {
  const float* X = (const float*)d_in[0];     // [B,S,H]
  const float* mask = (const float*)d_in[1];  // [B,1,1,S]
  const float* Wq = (const float*)d_in[2];
  const float* bq = (const float*)d_in[3];
  const float* Wk = (const float*)d_in[4];
  const float* bk = (const float*)d_in[5];
  const float* Wv = (const float*)d_in[6];
  const float* bv = (const float*)d_in[7];
  float* outp = (float*)d_out;  // fp32 (reference output dtype)

  // workspace: Q,K,V bf16 -> 24 MB total
  char* ws = (char*)d_ws;
  const size_t MB = 1 << 20;
  unsigned short* Qb = (unsigned short*)(ws + 0 * MB);   // 8 MB
  unsigned short* Kb = (unsigned short*)(ws + 8 * MB);   // 8 MB
  unsigned short* Vb = (unsigned short*)(ws + 16 * MB);  // 8 MB

  qkv_gemm<<<dim3(24, 32), 256, 0, stream>>>(X, Wq, Wk, Wv, bq, bk, bv, Qb, Kb,
                                             Vb);
  attn_kernel<<<dim3(32, 32), 256, 0, stream>>>(Qb, Kb, Vb, mask, outp);
}